// Round 1
// baseline (588.816 us; speedup 1.0000x reference)
//
#include <hip/hip_runtime.h>
#include <hip/hip_bf16.h>
#include <stdint.h>
#include <stddef.h>

#define NSP 110592      // 48^3
#define SD  48
#define SD2 2304        // 48*48
#define CIN 128
#define C3  384
#define NH  8
#define NB  2
#define NQ  84934656ull // NB*C3*NSP

typedef __hip_bfloat16 bf16;
typedef __bf16 bf16x8 __attribute__((ext_vector_type(8)));
typedef float  f32x4  __attribute__((ext_vector_type(4)));
typedef float  f32x2  __attribute__((ext_vector_type(2)));

// wbuf element offsets (all bf16): qkvw | dww | projw | temp
#define WOFF_QKVW 0
#define WOFF_DWW  49152
#define WOFF_PROJ 59520
#define WOFF_TEMP 75904
#define WTOTAL    75912

__device__ __forceinline__ float ldb(const bf16* p){ return __bfloat162float(*p); }
__device__ __forceinline__ float b2f(uint16_t u){
    union { float f; uint32_t i; } x; x.i = (uint32_t)u << 16; return x.f;
}
__device__ __forceinline__ uint16_t f2b(float f){
    bf16 h = __float2bfloat16(f); return *(uint16_t*)&h;
}
// packed-lane bf16 -> f32 (lo/hi halves of a dword)
__device__ __forceinline__ float blo(uint32_t u){
    union { float f; uint32_t i; } x; x.i = u << 16; return x.f;
}
__device__ __forceinline__ float bhi(uint32_t u){
    union { float f; uint32_t i; } x; x.i = u & 0xffff0000u; return x.f;
}

// ---- sniffer: flag=1 if inputs are fp32, 0 if bf16 ---------------------------
__global__ void k_sniff(const uint16_t* __restrict__ x16, int* __restrict__ flag)
{
    int t = threadIdx.x; int cnt = 0;
    for (int i = 0; i < 16; ++i) {
        uint16_t b = x16[(size_t)(t * 16 + i) * 2];   // even halves only
        int e = (b >> 7) & 0xFF;
        if (e >= 100 && e <= 140) ++cnt;              // bf16-exponent-plausible
    }
    for (int off = 32; off; off >>= 1) cnt += __shfl_down(cnt, off, 64);
    __shared__ int s[4];
    if ((t & 63) == 0) s[t >> 6] = cnt;
    __syncthreads();
    if (t == 0) *flag = (s[0] + s[1] + s[2] + s[3] < 2048) ? 1 : 0;
}

// ---- canonicalize all weights to bf16 in wbuf --------------------------------
__global__ void k_cvtw(const void* __restrict__ qw, const void* __restrict__ dw,
                       const void* __restrict__ pw, const void* __restrict__ tw,
                       bf16* __restrict__ wbuf, const int* __restrict__ flagp)
{
    int f = *flagp;
    int idx = blockIdx.x * 256 + threadIdx.x;
    if (idx >= WTOTAL) return;
    const void* src; int off;
    if (idx < WOFF_DWW)      { src = qw; off = idx; }
    else if (idx < WOFF_PROJ){ src = dw; off = idx - WOFF_DWW; }
    else if (idx < WOFF_TEMP){ src = pw; off = idx - WOFF_PROJ; }
    else                     { src = tw; off = idx - WOFF_TEMP; }
    float v = f ? ((const float*)src)[off]
                : __bfloat162float(((const bf16*)src)[off]);
    wbuf[idx] = __float2bfloat16(v);
}

// ---- K0: transpose x[b][c][n] -> xT[b][n][c] (bf16 out, dual-dtype in) -------
__global__ __launch_bounds__(256) void k_transpose(const void* __restrict__ xin,
                                                   bf16* __restrict__ xT,
                                                   const int* __restrict__ flagp)
{
    int f = *flagp;
    int b = blockIdx.y;
    size_t tid = (size_t)blockIdx.x * 256 + threadIdx.x;
    int c = (int)(tid & 127);
    size_t n8 = tid >> 7;
    size_t base = ((size_t)b * CIN + c) * NSP + n8 * 8;
    bf16 pv[8];
    if (f) {
        const float* src = (const float*)xin + base;
        float4 a = *(const float4*)src;
        float4 d = *(const float4*)(src + 4);
        pv[0] = __float2bfloat16(a.x); pv[1] = __float2bfloat16(a.y);
        pv[2] = __float2bfloat16(a.z); pv[3] = __float2bfloat16(a.w);
        pv[4] = __float2bfloat16(d.x); pv[5] = __float2bfloat16(d.y);
        pv[6] = __float2bfloat16(d.z); pv[7] = __float2bfloat16(d.w);
    } else {
        uint4 v = *(const uint4*)((const bf16*)xin + base);
        const bf16* q = (const bf16*)&v;
#pragma unroll
        for (int j = 0; j < 8; ++j) pv[j] = q[j];
    }
    bf16* dst = xT + ((size_t)b * NSP + n8 * 8) * CIN + c;
#pragma unroll
    for (int j = 0; j < 8; ++j) dst[(size_t)j * CIN] = pv[j];
}

// ---- GEMM  C[b][m][n] = A[m][k] * BT[b][n][k], K=128, 128x128 tiles ----------
__global__ __launch_bounds__(256) void k_gemm_bt(const bf16* __restrict__ A,
                                                 const bf16* __restrict__ BT,
                                                 void* __restrict__ Cout,
                                                 int Mtotal,
                                                 const int* __restrict__ flagp,
                                                 int mblocks)
{
    __shared__ __align__(16) bf16 lA[128 * CIN];
    __shared__ __align__(16) bf16 lB[128 * CIN];
    int b = blockIdx.z;
    int bx = blockIdx.x;
    int mb, nb;
    if (mblocks == 3) {
        int g = bx / 24, w = bx % 24;
        nb = g * 8 + (w & 7);
        mb = w >> 3;
    } else { mb = 0; nb = bx; }
    size_t nbase = (size_t)nb * 128;
    const bf16* gA = A + (size_t)mb * 128 * CIN;
    const bf16* gB = BT + ((size_t)b * NSP + nbase) * CIN;
    int t = threadIdx.x;
#pragma unroll
    for (int i = 0; i < 8; ++i) {
        int off = (i * 256 + t) * 8;
        *(uint4*)&lA[off] = *(const uint4*)&gA[off];
        *(uint4*)&lB[off] = *(const uint4*)&gB[off];
    }
    __syncthreads();

    int wave = t >> 6, lane = t & 63;
    int wm = (wave & 1) * 64, wn = (wave >> 1) * 64;
    int lr = lane & 15, lq = lane >> 4;
    f32x4 acc[4][4];
#pragma unroll
    for (int mi = 0; mi < 4; ++mi)
#pragma unroll
        for (int ni = 0; ni < 4; ++ni) acc[mi][ni] = (f32x4){0.f, 0.f, 0.f, 0.f};

#pragma unroll
    for (int ks = 0; ks < 4; ++ks) {
        int kof = ks * 32 + lq * 8;
        bf16x8 af[4], bfv[4];
#pragma unroll
        for (int mi = 0; mi < 4; ++mi)
            af[mi] = *(const bf16x8*)&lA[(wm + mi * 16 + lr) * CIN + kof];
#pragma unroll
        for (int ni = 0; ni < 4; ++ni)
            bfv[ni] = *(const bf16x8*)&lB[(wn + ni * 16 + lr) * CIN + kof];
#pragma unroll
        for (int mi = 0; mi < 4; ++mi)
#pragma unroll
            for (int ni = 0; ni < 4; ++ni)
                acc[mi][ni] = __builtin_amdgcn_mfma_f32_16x16x32_bf16(
                    af[mi], bfv[ni], acc[mi][ni], 0, 0, 0);
    }

    int f32o = flagp ? *flagp : 0;
    size_t cb = ((size_t)b * Mtotal + (size_t)mb * 128) * NSP + nbase;
    if (f32o) {
        float* Cb = (float*)Cout + cb;
#pragma unroll
        for (int mi = 0; mi < 4; ++mi)
#pragma unroll
            for (int ni = 0; ni < 4; ++ni)
#pragma unroll
                for (int r = 0; r < 4; ++r)
                    Cb[(size_t)(wm + mi * 16 + lq * 4 + r) * NSP + wn + ni * 16 + lr]
                        = acc[mi][ni][r];
    } else {
        bf16* Cb = (bf16*)Cout + cb;
#pragma unroll
        for (int mi = 0; mi < 4; ++mi)
#pragma unroll
            for (int ni = 0; ni < 4; ++ni)
#pragma unroll
                for (int r = 0; r < 4; ++r)
                    Cb[(size_t)(wm + mi * 16 + lq * 4 + r) * NSP + wn + ni * 16 + lr]
                        = __float2bfloat16(acc[mi][ni][r]);
    }
}

// ---- K2: depthwise 3x3x3 conv, LDS-tiled, 8-wide pk-fma strips ---------------
// grid (768, 12): block = (channel, 4-z output slab). LDS: 6 XOR-swizzled haloed
// planes of 50 rows x 64 cols bf16 (x-col d at LDS col 8+d; rows 0/49 + cols
// 0..7,56..63 are zero halo; byte ^= (row&7)<<4 kills the 128B-stride bank
// conflict). Compute: 288 strips of 8 d-columns x 4 z; per plane-row one
// b32+b128+b32 read (10 vals) and 12 v_pk_fma_f32 per weight-plane.
#define PLN 3200        // 64*50 elements per plane
#define PLB 6400        // plane bytes
__global__ __launch_bounds__(256, 4) void k_dwconv(const bf16* __restrict__ qkv1,
                                                   const bf16* __restrict__ dw,
                                                   bf16* __restrict__ qkv2,
                                                   float* __restrict__ sums)
{
    __shared__ __align__(16) bf16 lds[6 * PLN];
    __shared__ float red[4];
    int bc = blockIdx.x;
    int slab = blockIdx.y;
    int z0 = slab * 4;
    int ch = bc % C3;
    int t = threadIdx.x;
    const bf16* src = qkv1 + (size_t)bc * NSP;
    bf16* dst = qkv2 + (size_t)bc * NSP;

    float wgt[27];
#pragma unroll
    for (int i = 0; i < 27; ++i) wgt[i] = ldb(&dw[ch * 27 + i]);

    // phase 0: zero all of LDS (2400 uint4) — swizzle is a permutation, safe
#pragma unroll
    for (int i = 0; i < 10; ++i) {
        int idx = i * 256 + t;
        if (idx < 2400) *(uint4*)&lds[idx * 8] = (uint4){0, 0, 0, 0};
    }
    __syncthreads();

    // phase 1: stage 6 planes (z0-1 .. z0+4), 288 uint4 per plane, swizzled
#pragma unroll
    for (int i = 0; i < 7; ++i) {
        int vidx = i * 256 + t;
        if (vidx < 1728) {
            int p = vidx / 288;
            int rr = vidx - p * 288;
            int yy = rr / 6;
            int dg = rr - yy * 6;
            int zp = z0 - 1 + p;
            if ((unsigned)zp < SD) {
                uint4 v = *(const uint4*)&src[(size_t)zp * SD2 + yy * SD + dg * 8];
                int ab = p * PLB + (yy + 1) * 128 + 16 + dg * 16;
                ab ^= ((yy + 1) & 7) << 4;
                *(uint4*)((char*)lds + ab) = v;
            }
        }
    }
    __syncthreads();

    // phase 2: 288 strips: s -> y = s/6, d-base = (s%6)*8
    f32x2 ss2 = (f32x2){0.f, 0.f};
#pragma unroll 1
    for (int r = 0; r < 2; ++r) {
        int s = r * 256 + t;
        if (s < 288) {
            int y = s / 6;
            int c8 = (s - y * 6) * 8;
            // precompute swizzled in-plane byte offsets for the 3 rows
            int offL[3], offM[3], offR[3];
#pragma unroll
            for (int dy = 0; dy < 3; ++dy) {
                int row = y + dy;
                int sw = (row & 7) << 4;
                int rb = row * 128 + 2 * c8;
                offL[dy] = (rb + 12) ^ sw;   // cols 6..7   (use hi = v0)
                offM[dy] = (rb + 16) ^ sw;   // cols 8..15  (v1..v8)
                offR[dy] = (rb + 32) ^ sw;   // cols 16..17 (use lo = v9)
            }
            f32x2 acc2[4][4];
#pragma unroll
            for (int oz = 0; oz < 4; ++oz)
#pragma unroll
                for (int m = 0; m < 4; ++m) acc2[oz][m] = (f32x2){0.f, 0.f};

            const char* ldsb = (const char*)lds;
#pragma unroll
            for (int pl = 0; pl < 6; ++pl) {
                const char* Pb = ldsb + pl * PLB;
#pragma unroll
                for (int dy = 0; dy < 3; ++dy) {
                    uint32_t Lw = *(const uint32_t*)(Pb + offL[dy]);
                    uint4    Mw = *(const uint4*)   (Pb + offM[dy]);
                    uint32_t Rw = *(const uint32_t*)(Pb + offR[dy]);
                    // f[0..9] = window cols 7+c8 .. 16+c8 as f32
                    f32x2 vb0 = (f32x2){blo(Mw.x), bhi(Mw.x)};   // f1,f2
                    f32x2 vb1 = (f32x2){blo(Mw.y), bhi(Mw.y)};   // f3,f4
                    f32x2 vb2 = (f32x2){blo(Mw.z), bhi(Mw.z)};   // f5,f6
                    f32x2 vb3 = (f32x2){blo(Mw.w), bhi(Mw.w)};   // f7,f8
                    f32x2 va0 = (f32x2){bhi(Lw),   blo(Mw.x)};   // f0,f1
                    f32x2 va1 = (f32x2){bhi(Mw.x), blo(Mw.y)};   // f2,f3
                    f32x2 va2 = (f32x2){bhi(Mw.y), blo(Mw.z)};   // f4,f5
                    f32x2 va3 = (f32x2){bhi(Mw.z), blo(Mw.w)};   // f6,f7
                    f32x2 va4 = (f32x2){bhi(Mw.w), blo(Rw)};     // f8,f9
#pragma unroll
                    for (int wp = 0; wp < 3; ++wp) {
                        int oz = pl - wp;
                        if (oz < 0 || oz > 3) continue;   // compile-time
                        int wb = wp * 9 + dy * 3;
                        float w0 = wgt[wb], w1 = wgt[wb + 1], w2 = wgt[wb + 2];
                        f32x2 w0p = (f32x2){w0, w0};
                        f32x2 w1p = (f32x2){w1, w1};
                        f32x2 w2p = (f32x2){w2, w2};
                        acc2[oz][0] = __builtin_elementwise_fma(va0, w0p, acc2[oz][0]);
                        acc2[oz][1] = __builtin_elementwise_fma(va1, w0p, acc2[oz][1]);
                        acc2[oz][2] = __builtin_elementwise_fma(va2, w0p, acc2[oz][2]);
                        acc2[oz][3] = __builtin_elementwise_fma(va3, w0p, acc2[oz][3]);
                        acc2[oz][0] = __builtin_elementwise_fma(vb0, w1p, acc2[oz][0]);
                        acc2[oz][1] = __builtin_elementwise_fma(vb1, w1p, acc2[oz][1]);
                        acc2[oz][2] = __builtin_elementwise_fma(vb2, w1p, acc2[oz][2]);
                        acc2[oz][3] = __builtin_elementwise_fma(vb3, w1p, acc2[oz][3]);
                        acc2[oz][0] = __builtin_elementwise_fma(va1, w2p, acc2[oz][0]);
                        acc2[oz][1] = __builtin_elementwise_fma(va2, w2p, acc2[oz][1]);
                        acc2[oz][2] = __builtin_elementwise_fma(va3, w2p, acc2[oz][2]);
                        acc2[oz][3] = __builtin_elementwise_fma(va4, w2p, acc2[oz][3]);
                    }
                }
            }
            // store 4 rows of 8 bf16 + squared-sum
#pragma unroll
            for (int oz = 0; oz < 4; ++oz) {
                uint4 o;
                o.x = (uint32_t)f2b(acc2[oz][0].x) | ((uint32_t)f2b(acc2[oz][0].y) << 16);
                o.y = (uint32_t)f2b(acc2[oz][1].x) | ((uint32_t)f2b(acc2[oz][1].y) << 16);
                o.z = (uint32_t)f2b(acc2[oz][2].x) | ((uint32_t)f2b(acc2[oz][2].y) << 16);
                o.w = (uint32_t)f2b(acc2[oz][3].x) | ((uint32_t)f2b(acc2[oz][3].y) << 16);
                *(uint4*)&dst[(size_t)(z0 + oz) * SD2 + y * SD + c8] = o;
#pragma unroll
                for (int m = 0; m < 4; ++m)
                    ss2 = __builtin_elementwise_fma(acc2[oz][m], acc2[oz][m], ss2);
            }
        }
    }

    float ssq = ss2.x + ss2.y;
    for (int off = 32; off; off >>= 1) ssq += __shfl_down(ssq, off, 64);
    if ((t & 63) == 0) red[t >> 6] = ssq;
    __syncthreads();
    if (t == 0) atomicAdd(&sums[bc], red[0] + red[1] + red[2] + red[3]);
}

// ---- K3: scores S[b][h][i][j] = sum_n q_i k_j  (MFMA, full n coverage) -------
__global__ __launch_bounds__(256) void k_scores(const bf16* __restrict__ qkv2,
                                                float* __restrict__ scores)
{
    int b = blockIdx.z, h = blockIdx.y;
    const bf16* qb = qkv2 + ((size_t)b * C3 + h * 16) * NSP;
    const bf16* kb = qkv2 + ((size_t)b * C3 + 128 + h * 16) * NSP;
    int t = threadIdx.x, w = t >> 6, lane = t & 63;
    int m = lane & 15, q4 = lane >> 4;
    size_t n0 = (size_t)blockIdx.x * 1024 + (size_t)w * 256 + (size_t)q4 * 8;
    const bf16* qp = qb + (size_t)m * NSP + n0;
    const bf16* kp = kb + (size_t)m * NSP + n0;
    f32x4 acc = (f32x4){0.f, 0.f, 0.f, 0.f};
#pragma unroll
    for (int it = 0; it < 8; ++it) {
        bf16x8 a  = *(const bf16x8*)(qp + it * 32);
        bf16x8 bb = *(const bf16x8*)(kp + it * 32);
        acc = __builtin_amdgcn_mfma_f32_16x16x32_bf16(a, bb, acc, 0, 0, 0);
    }
    float* srow = scores + (size_t)(b * NH + h) * 256;
#pragma unroll
    for (int r = 0; r < 4; ++r)
        atomicAdd(&srow[(q4 * 4 + r) * 16 + m], acc[r]);
}

// ---- K4: normalize + temperature + softmax -----------------------------------
__global__ void k_softmax(const float* __restrict__ scores,
                          const float* __restrict__ sums,
                          const bf16* __restrict__ temp,
                          float* __restrict__ attn)
{
    int t = threadIdx.x;             // t = b*128 + h*16 + i
    int h = (t >> 4) & 7, b = t >> 7;
    float tau = __bfloat162float(temp[h]);
    float invq = 1.f / fmaxf(sqrtf(sums[b * C3 + (t & 127)]), 1e-12f);
    const float* srow = scores + (size_t)t * 16;
    float s[16]; float mx = -3.4e38f;
#pragma unroll
    for (int j = 0; j < 16; ++j) {
        float invk = 1.f / fmaxf(sqrtf(sums[b * C3 + 128 + h * 16 + j]), 1e-12f);
        s[j] = srow[j] * invq * invk * tau;
        mx = fmaxf(mx, s[j]);
    }
    float sum = 0.f;
#pragma unroll
    for (int j = 0; j < 16; ++j) { s[j] = expf(s[j] - mx); sum += s[j]; }
    float inv = 1.f / sum;
    float* arow = attn + (size_t)t * 16;
#pragma unroll
    for (int j = 0; j < 16; ++j) arow[j] = s[j] * inv;
}

// ---- K5: outT[b][n][h*16+i] = sum_j attn[i][j] v[j][n] -----------------------
__global__ __launch_bounds__(256) void k_av(const bf16* __restrict__ qkv2,
                                            const float* __restrict__ attn,
                                            bf16* __restrict__ outT)
{
    int b = blockIdx.z, h = blockIdx.y;
    const bf16* vb = qkv2 + ((size_t)b * C3 + 256 + h * 16) * NSP;
    __shared__ float at[256];        // at[j*16+i]
    int t = threadIdx.x;
    {
        int i = t >> 4, j = t & 15;
        at[j * 16 + i] = attn[(size_t)(b * NH + h) * 256 + t];
    }
    __syncthreads();
    size_t n0 = (size_t)blockIdx.x * 1024 + (size_t)t * 4;
    float acc[16][4];
#pragma unroll
    for (int i = 0; i < 16; ++i)
#pragma unroll
        for (int k = 0; k < 4; ++k) acc[i][k] = 0.f;
#pragma unroll
    for (int j = 0; j < 16; ++j) {
        uint2 raw = *(const uint2*)&vb[(size_t)j * NSP + n0];
        const bf16* rp = (const bf16*)&raw;
        float vf[4];
#pragma unroll
        for (int k = 0; k < 4; ++k) vf[k] = ldb(&rp[k]);
#pragma unroll
        for (int i = 0; i < 16; ++i) {
            float wv = at[j * 16 + i];
#pragma unroll
            for (int k = 0; k < 4; ++k) acc[i][k] += wv * vf[k];
        }
    }
    bf16* ob = outT + ((size_t)b * NSP + n0) * CIN + h * 16;
#pragma unroll
    for (int k = 0; k < 4; ++k) {
        bf16 tmp[16];
#pragma unroll
        for (int i = 0; i < 16; ++i) tmp[i] = __float2bfloat16(acc[i][k]);
        *(uint4*)&ob[(size_t)k * CIN]     = *(uint4*)&tmp[0];
        *(uint4*)&ob[(size_t)k * CIN + 8] = *(uint4*)&tmp[8];
    }
}

// ---- host --------------------------------------------------------------------
extern "C" void kernel_launch(void* const* d_in, const int* in_sizes, int n_in,
                              void* d_out, int out_size, void* d_ws, size_t ws_size,
                              hipStream_t stream)
{
    const void *px = nullptr, *pq = nullptr, *pd = nullptr, *pp = nullptr, *pt = nullptr;
    for (int i = 0; i < n_in; ++i) {
        switch (in_sizes[i]) {
            case 28311552: px = d_in[i]; break;   // x
            case 49152:    pq = d_in[i]; break;   // qkv_w
            case 10368:    pd = d_in[i]; break;   // dw_w
            case 16384:    pp = d_in[i]; break;   // proj_w
            case 8:        pt = d_in[i]; break;   // temperature
        }
    }
    const size_t required = NQ * 4 + (1u << 20);
    if (!px || !pq || !pd || !pp || !pt || ws_size < required) {
        (void)hipMemsetAsync(d_out, 0, (size_t)out_size * 2, stream);
        return;
    }

    char* ws = (char*)d_ws;
    bf16* qkv1 = (bf16*)ws;                       // NQ bf16
    bf16* qkv2 = (bf16*)(ws + NQ * 2);            // NQ bf16
    char* small = ws + NQ * 4;
    int*   flag   = (int*)small;
    float* sums   = (float*)(small + 256);
    float* scores = (float*)(small + 8192);
    float* attn   = (float*)(small + 24576);
    bf16*  wbuf   = (bf16*)(small + 40960);
    bf16* xT   = qkv2;   // alias: dead before k_dwconv writes qkv2
    bf16* outT = qkv1;   // alias: qkv1 dead after k_dwconv

    (void)hipMemsetAsync(small, 0, 40960, stream);  // flag, sums, scores, attn
    k_sniff<<<1, 256, 0, stream>>>((const uint16_t*)px, flag);
    k_cvtw<<<(WTOTAL + 255) / 256, 256, 0, stream>>>(pq, pd, pp, pt, wbuf, flag);
    k_transpose<<<dim3(6912, NB), 256, 0, stream>>>(px, xT, flag);
    k_gemm_bt<<<dim3(864 * 3, 1, NB), 256, 0, stream>>>(
        wbuf + WOFF_QKVW, xT, qkv1, C3, nullptr, 3);
    k_dwconv<<<dim3(NB * C3, 12), 256, 0, stream>>>(qkv1, wbuf + WOFF_DWW, qkv2, sums);
    k_scores<<<dim3(108, NH, NB), 256, 0, stream>>>(qkv2, scores);
    k_softmax<<<1, 256, 0, stream>>>(scores, sums, wbuf + WOFF_TEMP, attn);
    k_av<<<dim3(108, NH, NB), 256, 0, stream>>>(qkv2, attn, outT);
    k_gemm_bt<<<dim3(864, 1, NB), 256, 0, stream>>>(
        wbuf + WOFF_PROJ, outT, d_out, CIN, flag, 1);
}